// Round 13
// baseline (722.078 us; speedup 1.0000x reference)
//
#include <hip/hip_runtime.h>
#include <hip/hip_bf16.h>

// B=2, S=2048, D=2048, H=16, I=8192, HD=512; M = B*S = 4096.

typedef __bf16 bf16x8 __attribute__((ext_vector_type(8)));
typedef float f32x4 __attribute__((ext_vector_type(4)));
typedef float f32x16 __attribute__((ext_vector_type(16)));

__device__ __forceinline__ unsigned short f2bf(float f) {
    union { float f; unsigned int u; } x; x.f = f;
    unsigned int r = x.u + 0x7fffu + ((x.u >> 16) & 1u);  // RNE
    return (unsigned short)(r >> 16);
}
__device__ __forceinline__ float bf2f(unsigned short b) {
    union { unsigned int u; float f; } x; x.u = ((unsigned int)b) << 16;
    return x.f;
}

__device__ __forceinline__ void gload_lds16(const void* g, void* l) {
    __builtin_amdgcn_global_load_lds((const __attribute__((address_space(1))) void*)g,
                                     (__attribute__((address_space(3))) void*)l,
                                     16, 0, 0);
}

// ---------------- prep kernels (frozen) ----------------

__global__ void conv_kernel(const float* __restrict__ in, unsigned short* __restrict__ out) {
    size_t i = ((size_t)blockIdx.x * 256 + threadIdx.x) * 4;
    float4 v = *(const float4*)(in + i);
    ushort4 o; o.x = f2bf(v.x); o.y = f2bf(v.y); o.z = f2bf(v.z); o.w = f2bf(v.w);
    *(ushort4*)(out + i) = o;
}

__global__ void tconv_kernel(const float* __restrict__ in, unsigned short* __restrict__ out,
                             int R, int C) {
    __shared__ float tile[64][65];
    int nbc = C >> 6;
    int bc = blockIdx.x % nbc, br = blockIdx.x / nbc;
    int r0 = br * 64, c0 = bc * 64;
    int t = threadIdx.x;
#pragma unroll
    for (int i = 0; i < 4; ++i) {
        int idx = i * 256 + t;
        int r = idx >> 4, c4 = (idx & 15) * 4;
        float4 v = *(const float4*)(in + (size_t)(r0 + r) * C + c0 + c4);
        tile[r][c4] = v.x; tile[r][c4 + 1] = v.y; tile[r][c4 + 2] = v.z; tile[r][c4 + 3] = v.w;
    }
    __syncthreads();
#pragma unroll
    for (int i = 0; i < 4; ++i) {
        int idx = i * 256 + t;
        int c = idx >> 4, r4 = (idx & 15) * 4;
        ushort4 o;
        o.x = f2bf(tile[r4][c]); o.y = f2bf(tile[r4 + 1][c]);
        o.z = f2bf(tile[r4 + 2][c]); o.w = f2bf(tile[r4 + 3][c]);
        *(ushort4*)(out + (size_t)(c0 + c) * R + r0 + r4) = o;
    }
}

// ---------------- GEMM 1 fused: gate+up — 32x32x16 MFMA (NEW) ----------------
// Same r12 staging/pipeline/XCD-chunks; frag reads + MFMA + epilogue converted to
// the 32x32x16 shape (m119: ~15-20% better per-FLOP matrix-pipe rate).
// C/D layout: col=lane&31, row=(reg&3)+8*(reg>>2)+4*(lane>>5)  [m74/m101 verified].
__global__ void __launch_bounds__(512, 2) gemm_gu(
    const unsigned short* __restrict__ xb,    // 4096 x 2048
    const unsigned short* __restrict__ WgT,   // 8192 x 2048
    const unsigned short* __restrict__ WuT,   // 8192 x 2048
    unsigned short* __restrict__ hhT)         // (2*8192) x 2048
{
    const int K = 2048;
    __shared__ unsigned short LDS[4][16384];  // 128 KB
    int bid = (int)blockIdx.x;
    int xcd = bid & 7, idx = bid >> 3;        // bijective: 1024 = 8 XCD * 128
    int mt = idx & 15;                        // all 16 mt per XCD
    int nt = xcd * 8 + (idx >> 4);            // 8 nt per XCD
    int tid = threadIdx.x, lane = tid & 63, wave = tid >> 6;
    int wm = wave >> 1, wn = wave & 1;        // 4M x 2N waves, wave tile 64x64
    int m31 = lane & 31, k2 = lane >> 5;

    f32x16 accg[2][2] = {};
    f32x16 accu[2][2] = {};

    // staging (unchanged from r12)
    int jl = (lane & 7) ^ (lane >> 3);
    int prowA = wave * 16 + (lane >> 3);
    int rowA0 = prowA + ((jl & 4) << 5);
    int ccA = (jl & 3) << 3;
    const unsigned short* srcA0 = xb + (size_t)(mt * 256 + rowA0) * K + ccA;
    const unsigned short* srcA1 = srcA0 + (size_t)8 * K;
    int prowB = tid >> 3;
    int jbl = (tid & 7) ^ (prowB & 7);
    int rowB0 = prowB + ((jbl & 4) << 4);
    int ccB = (jbl & 3) << 3;
    const unsigned short* srcBg = WgT + (size_t)(nt * 128 + rowB0) * K + ccB;
    const unsigned short* srcBu = WuT + (size_t)(nt * 128 + rowB0) * K + ccB;

    // 32x32x16 fragment byte offsets within a buffer
    // A: row rl = wm*64 + mf*32 + m31 in paired [128 prow][8 chunk]; chunk = s*2+k2 (+4 if hi)
    int aA[2][2], aBg[2][2], aBu[2][2];
#pragma unroll
    for (int mf = 0; mf < 2; ++mf) {
        int rl = wm * 64 + mf * 32 + m31;      // 0..255
        int pr = rl & 127, hi = rl >> 7;
#pragma unroll
        for (int s = 0; s < 2; ++s) {
            int ch = s * 2 + k2 + hi * 4;
            aA[mf][s] = pr * 128 + ((ch ^ (pr & 7)) << 4);
        }
    }
#pragma unroll
    for (int nf = 0; nf < 2; ++nf) {
        int rl = wn * 64 + nf * 32 + m31;      // 0..127
        int pr = rl & 63, hi = rl >> 6;
#pragma unroll
        for (int s = 0; s < 2; ++s) {
            int ch = s * 2 + k2 + hi * 4;
            aBg[nf][s] = 16384 + pr * 128 + ((ch ^ (pr & 7)) << 4);
            aBu[nf][s] = aBg[nf][s] + 8192;
        }
    }

#define GU_STAGE_A(t_) do {                                                              \
        char* dA = (char*)&LDS[(t_) & 3][0] + wave * 2048;                               \
        gload_lds16((const void*)(srcA0 + (size_t)(t_) * 32), (void*)dA);                \
        gload_lds16((const void*)(srcA1 + (size_t)(t_) * 32), (void*)(dA + 1024));       \
    } while (0)
#define GU_STAGE_B(t_) do {                                                              \
        char* dB = (char*)&LDS[(t_) & 3][8192] + wave * 1024;                            \
        gload_lds16((const void*)(srcBg + (size_t)(t_) * 32), (void*)dB);                \
        gload_lds16((const void*)(srcBu + (size_t)(t_) * 32), (void*)(dB + 8192));       \
    } while (0)

    GU_STAGE_A(0); GU_STAGE_B(0);
    GU_STAGE_A(1); GU_STAGE_B(1);
    GU_STAGE_A(2); GU_STAGE_B(2);

    for (int t = 0; t < 64; ++t) {
        if (t + 2 < 64)      asm volatile("s_waitcnt vmcnt(8)" ::: "memory");
        else if (t + 1 < 64) asm volatile("s_waitcnt vmcnt(4)" ::: "memory");
        else                 asm volatile("s_waitcnt vmcnt(0)" ::: "memory");
        __builtin_amdgcn_s_barrier();
        const char* Abase = (const char*)&LDS[t & 3][0];
        bool more = (t + 3) < 64;
        // ---- phase 0: gate ----
        bf16x8 af[2][2], bfg[2][2], bfu[2][2];
#pragma unroll
        for (int nf = 0; nf < 2; ++nf)
#pragma unroll
            for (int s = 0; s < 2; ++s) bfg[nf][s] = *(const bf16x8*)(Abase + aBg[nf][s]);
#pragma unroll
        for (int mf = 0; mf < 2; ++mf)
#pragma unroll
            for (int s = 0; s < 2; ++s) af[mf][s] = *(const bf16x8*)(Abase + aA[mf][s]);
        if (more) GU_STAGE_A(t + 3);
        __builtin_amdgcn_s_barrier();
        asm volatile("s_waitcnt lgkmcnt(0)" ::: "memory");
        __builtin_amdgcn_s_setprio(1);
#pragma unroll
        for (int mf = 0; mf < 2; ++mf)
#pragma unroll
            for (int nf = 0; nf < 2; ++nf)
#pragma unroll
                for (int s = 0; s < 2; ++s)
                    accg[mf][nf] = __builtin_amdgcn_mfma_f32_32x32x16_bf16(af[mf][s], bfg[nf][s], accg[mf][nf], 0, 0, 0);
        __builtin_amdgcn_s_setprio(0);
        __builtin_amdgcn_s_barrier();
        // ---- phase 1: up (A-frags reused from registers) ----
#pragma unroll
        for (int nf = 0; nf < 2; ++nf)
#pragma unroll
            for (int s = 0; s < 2; ++s) bfu[nf][s] = *(const bf16x8*)(Abase + aBu[nf][s]);
        if (more) GU_STAGE_B(t + 3);
        __builtin_amdgcn_s_barrier();
        asm volatile("s_waitcnt lgkmcnt(0)" ::: "memory");
        __builtin_amdgcn_s_setprio(1);
#pragma unroll
        for (int mf = 0; mf < 2; ++mf)
#pragma unroll
            for (int nf = 0; nf < 2; ++nf)
#pragma unroll
                for (int s = 0; s < 2; ++s)
                    accu[mf][nf] = __builtin_amdgcn_mfma_f32_32x32x16_bf16(af[mf][s], bfu[nf][s], accu[mf][nf], 0, 0, 0);
        __builtin_amdgcn_s_setprio(0);
    }
#undef GU_STAGE_A
#undef GU_STAGE_B

    // epilogue: h = silu(g)*u -> hhT, 32x32 C/D mapping
    int b = mt >> 3;
#pragma unroll
    for (int mf = 0; mf < 2; ++mf)
#pragma unroll
        for (int nf = 0; nf < 2; ++nf) {
            int n = nt * 128 + wn * 64 + nf * 32 + m31;
#pragma unroll
            for (int rg = 0; rg < 4; ++rg) {
                int row = mt * 256 + wm * 64 + mf * 32 + rg * 8 + k2 * 4;
                ushort4 hv;
#pragma unroll
                for (int r = 0; r < 4; ++r) {
                    float g = accg[mf][nf][rg * 4 + r];
                    float u = accu[mf][nf][rg * 4 + r];
                    float h = g / (1.f + __expf(-g)) * u;
                    ((unsigned short*)&hv)[r] = f2bf(h);
                }
                *(ushort4*)(hhT + ((size_t)b * 8192 + n) * 2048 + (row & 2047)) = hv;
            }
        }
}

// ---------------- GEMM 2 v5: agg + GIN (r12 form, frozen) ----------------
__global__ void __launch_bounds__(512, 2) gemm_agg4(
    const float* __restrict__ adj,            // (B*H=32) x S x S f32
    const unsigned short* __restrict__ hhT,   // (B*I) x S bf16
    const float* __restrict__ eps, const float* __restrict__ alpha,
    unsigned short* __restrict__ hcomb)       // (B*S) x I bf16
{
    const int S = 2048, HD = 512, I = 8192;
    __shared__ unsigned short As[2][128 * 40];   // 2 x 10 KB, padded 80B rows
    __shared__ unsigned short Bs[4][512 * 32];   // 4 x 32 KB, paired-row swizzled
    int bid = (int)blockIdx.x;
    int lb = (bid & 7) * 64 + (bid >> 3);
    int pair = lb >> 4;
    int mt = lb & 15;
    int b = pair >> 4, h = pair & 15;
    int tid = threadIdx.x, lane = tid & 63, wave = tid >> 6;
    int wm = wave >> 2, wn = wave & 3;
    int l15 = lane & 15, l4 = lane >> 4;
    f32x4 acc[4][8] = {};

    float e1 = 1.f + eps[h];
    float a1 = alpha[h];
    bool a1z = (a1 == 0.f);
    float dfac = a1z ? 0.f : (e1 / a1);

    const float* Ab = adj + ((size_t)pair * S + (size_t)mt * 128) * S;
    const unsigned short* Bb = hhT + ((size_t)b * I + (size_t)h * HD) * (size_t)S;

    int a_row0 = tid >> 3, a_c = (tid & 7) << 2;
    int grow0 = mt * 128 + a_row0;

    int jl = (lane & 7) ^ (lane >> 3);
    int prow0 = wave * 16 + (lane >> 3);
    int browB = prow0 + ((jl & 4) << 6);
    int ccB = (jl & 3) << 3;
    const unsigned short* srcB = Bb + (size_t)browB * S + ccB;

#define BSTAGE(t_) do {                                                           \
        char* d_ = (char*)&Bs[(t_) & 3][0] + wave * 2048;                         \
        const unsigned short* s_ = srcB + (size_t)(t_) * 32;                      \
        gload_lds16((const void*)s_, (void*)d_);                                  \
        gload_lds16((const void*)(s_ + (size_t)8 * S), (void*)(d_ + 1024));       \
        gload_lds16((const void*)(s_ + (size_t)128 * S), (void*)(d_ + 16384));    \
        gload_lds16((const void*)(s_ + (size_t)136 * S), (void*)(d_ + 17408));    \
    } while (0)

    float4 pa0_0, pa1_0, pa0_1, pa1_1;

#define ALOAD(SET, K0)                                                            \
    do {                                                                          \
        pa0_##SET = *(const float4*)(Ab + (size_t)a_row0 * S + (K0) + a_c);       \
        pa1_##SET = *(const float4*)(Ab + (size_t)(a_row0 + 64) * S + (K0) + a_c);\
    } while (0)

#define ACONV(SET, BUF, K0)                                                       \
    do {                                                                          \
        int j0 = grow0 - (K0) - a_c;                                              \
        pa0_##SET.x += (j0 == 0) ? dfac : 0.f;                                    \
        pa0_##SET.y += (j0 == 1) ? dfac : 0.f;                                    \
        pa0_##SET.z += (j0 == 2) ? dfac : 0.f;                                    \
        pa0_##SET.w += (j0 == 3) ? dfac : 0.f;                                    \
        int j1 = j0 + 64;                                                         \
        pa1_##SET.x += (j1 == 0) ? dfac : 0.f;                                    \
        pa1_##SET.y += (j1 == 1) ? dfac : 0.f;                                    \
        pa1_##SET.z += (j1 == 2) ? dfac : 0.f;                                    \
        pa1_##SET.w += (j1 == 3) ? dfac : 0.f;                                    \
        ushort4 o0, o1;                                                           \
        o0.x = f2bf(pa0_##SET.x); o0.y = f2bf(pa0_##SET.y);                       \
        o0.z = f2bf(pa0_##SET.z); o0.w = f2bf(pa0_##SET.w);                       \
        o1.x = f2bf(pa1_##SET.x); o1.y = f2bf(pa1_##SET.y);                       \
        o1.z = f2bf(pa1_##SET.z); o1.w = f2bf(pa1_##SET.w);                       \
        *(ushort4*)((char*)As[BUF] + a_row0 * 80 + a_c * 2) = o0;                 \
        *(ushort4*)((char*)As[BUF] + (a_row0 + 64) * 80 + a_c * 2) = o1;          \
    } while (0)

    int koff2 = l4 << 4;
    const char* aptr0 = (const char*)As[0] + (wm * 64 + l15) * 80 + koff2;
    const char* aptr1 = (const char*)As[1] + (wm * 64 + l15) * 80 + koff2;
    int cB = ((wn & 1) * 128 + l15) * 128 + (((l4 + ((wn >> 1) << 2)) ^ (l15 & 7)) << 4);

#define AGG_COMPUTE(APTR, BBASE)                                                        \
    do {                                                                                \
        bf16x8 af[4], bfv[8];                                                           \
        _Pragma("unroll")                                                               \
        for (int mi = 0; mi < 4; ++mi) af[mi] = *(const bf16x8*)((APTR) + mi * 16 * 80);\
        _Pragma("unroll")                                                               \
        for (int ni = 0; ni < 8; ++ni) bfv[ni] = *(const bf16x8*)((BBASE) + cB + ni * 2048);\
        __builtin_amdgcn_s_setprio(1);                                                  \
        _Pragma("unroll")                                                               \
        for (int mi = 0; mi < 4; ++mi)                                                  \
            _Pragma("unroll")                                                           \
            for (int ni = 0; ni < 8; ++ni)                                              \
                acc[mi][ni] = __builtin_amdgcn_mfma_f32_16x16x32_bf16(af[mi], bfv[ni],  \
                                                                      acc[mi][ni], 0, 0, 0); \
        __builtin_amdgcn_s_setprio(0);                                                  \
    } while (0)

    BSTAGE(0);
    ALOAD(0, 0);
    BSTAGE(1);
    ALOAD(1, 32);
    BSTAGE(2);
    ACONV(0, 0, 0);
    asm volatile("s_waitcnt lgkmcnt(0)" ::: "memory");
    __builtin_amdgcn_s_barrier();

    for (int s = 0; s < 64; s += 2) {
        AGG_COMPUTE(aptr0, (const char*)&Bs[s & 3][0]);
        ACONV(1, 1, (s + 1) * 32);
        if (s + 2 < 64) ALOAD(0, (s + 2) * 32);
        if (s + 3 < 64) BSTAGE(s + 3);
        asm volatile("s_waitcnt lgkmcnt(0)" ::: "memory");
        __builtin_amdgcn_s_barrier();
        AGG_COMPUTE(aptr1, (const char*)&Bs[(s + 1) & 3][0]);
        if (s + 2 < 64) {
            ACONV(0, 0, (s + 2) * 32);
            if (s + 3 < 64) ALOAD(1, (s + 3) * 32);
            if (s + 4 < 64) BSTAGE(s + 4);
            asm volatile("s_waitcnt lgkmcnt(0)" ::: "memory");
            __builtin_amdgcn_s_barrier();
        }
    }
#undef BSTAGE
#undef ALOAD
#undef ACONV
#undef AGG_COMPUTE

    int s_base = mt * 128 + wm * 64;
    int d_base = wn * 128;
    if (!a1z) {
#pragma unroll
        for (int mi = 0; mi < 4; ++mi)
#pragma unroll
            for (int ni = 0; ni < 8; ++ni) {
                int sb = s_base + mi * 16 + ((lane >> 4) << 2);
                int d = d_base + ni * 16 + (lane & 15);
#pragma unroll
                for (int r = 0; r < 4; ++r) {
                    size_t off = ((size_t)(b * S + sb + r)) * I + (size_t)h * HD + d;
                    hcomb[off] = f2bf(a1 * acc[mi][ni][r]);
                }
            }
    } else {
        // alpha == 0 fallback (never taken in bench)
#pragma unroll
        for (int mi = 0; mi < 4; ++mi)
#pragma unroll
            for (int ni = 0; ni < 8; ++ni) {
                int sb = s_base + mi * 16 + ((lane >> 4) << 2);
                int d = d_base + ni * 16 + (lane & 15);
                size_t col = (size_t)h * HD + d;
                ushort4 hq = *(const ushort4*)(hhT + ((size_t)b * I + col) * S + sb);
#pragma unroll
                for (int r = 0; r < 4; ++r) {
                    size_t off = ((size_t)(b * S + sb + r)) * I + col;
                    hcomb[off] = f2bf(e1 * bf2f(((const unsigned short*)&hq)[r]));
                }
            }
    }
}

// ---------------- GEMM 3: final projection — 32x32x16 MFMA (NEW) ----------------
// r12 staging/pipeline/XCD chunks; frag reads + MFMA + store converted.
__global__ void __launch_bounds__(512, 2) gemm_out2(
    const unsigned short* __restrict__ hcomb, // 4096 x 8192
    const unsigned short* __restrict__ WdT,   // 2048 x 8192
    float* __restrict__ out)                  // 4096 x 2048
{
    const int K = 8192;
    __shared__ unsigned short LDS[6][12288];  // 144 KB: per buf A 16 KB + B 8 KB
    int bid = (int)blockIdx.x;
    int xcd = bid & 7, idx = bid >> 3;        // bijective: 256 = 8 XCD * 32
    int mt = (xcd >> 1) * 4 + (idx & 3);      // 4 mt per XCD
    int nt = (xcd & 1) * 8 + (idx >> 2);      // 8 nt per XCD
    int tid = threadIdx.x, lane = tid & 63, wave = tid >> 6;
    int wm = wave >> 1, wn = wave & 1;        // 4M x 2N waves, wave tile 64x64
    int m31 = lane & 31, k2 = lane >> 5;
    f32x16 acc[2][2] = {};

    int jl = (lane & 7) ^ (lane >> 3);
    int prowA = wave * 16 + (lane >> 3);
    int rowA0 = prowA + ((jl & 4) << 5);
    int ccA = (jl & 3) << 3;
    const unsigned short* srcA0 = hcomb + (size_t)(mt * 256 + rowA0) * K + ccA;
    const unsigned short* srcA1 = srcA0 + (size_t)8 * K;
    int prowB = tid >> 3;
    int jbl = (tid & 7) ^ (prowB & 7);
    int rowB0 = prowB + ((jbl & 4) << 4);
    int ccB = (jbl & 3) << 3;
    const unsigned short* srcB0 = WdT + (size_t)(nt * 128 + rowB0) * K + ccB;

    // 32x32x16 fragment byte offsets
    int aA[2][2], aB[2][2];
#pragma unroll
    for (int mf = 0; mf < 2; ++mf) {
        int rl = wm * 64 + mf * 32 + m31;      // 0..255
        int pr = rl & 127, hi = rl >> 7;
#pragma unroll
        for (int s = 0; s < 2; ++s) {
            int ch = s * 2 + k2 + hi * 4;
            aA[mf][s] = pr * 128 + ((ch ^ (pr & 7)) << 4);
        }
    }
#pragma unroll
    for (int nf = 0; nf < 2; ++nf) {
        int rl = wn * 64 + nf * 32 + m31;      // 0..127
        int pr = rl & 63, hi = rl >> 6;
#pragma unroll
        for (int s = 0; s < 2; ++s) {
            int ch = s * 2 + k2 + hi * 4;
            aB[nf][s] = 16384 + pr * 128 + ((ch ^ (pr & 7)) << 4);
        }
    }

#define OSTAGE(t_) do {                                                                  \
        char* dA = (char*)&LDS[(t_) % 6][0] + wave * 2048;                               \
        gload_lds16((const void*)(srcA0 + (size_t)(t_) * 32), (void*)dA);                \
        gload_lds16((const void*)(srcA1 + (size_t)(t_) * 32), (void*)(dA + 1024));       \
        char* dB = (char*)&LDS[(t_) % 6][8192] + wave * 1024;                            \
        gload_lds16((const void*)(srcB0 + (size_t)(t_) * 32), (void*)dB);                \
    } while (0)

    OSTAGE(0); OSTAGE(1); OSTAGE(2); OSTAGE(3);

    for (int t = 0; t < 256; ++t) {
        if (t + 3 < 256)      asm volatile("s_waitcnt vmcnt(9)" ::: "memory");
        else if (t + 2 < 256) asm volatile("s_waitcnt vmcnt(6)" ::: "memory");
        else if (t + 1 < 256) asm volatile("s_waitcnt vmcnt(3)" ::: "memory");
        else                  asm volatile("s_waitcnt vmcnt(0)" ::: "memory");
        __builtin_amdgcn_s_barrier();
        const char* Abase = (const char*)&LDS[t % 6][0];
        bool more = (t + 4) < 256;
        bf16x8 af[2][2], bf[2][2];
#pragma unroll
        for (int nf = 0; nf < 2; ++nf)
#pragma unroll
            for (int s = 0; s < 2; ++s) bf[nf][s] = *(const bf16x8*)(Abase + aB[nf][s]);
        if (more) OSTAGE(t + 4);
#pragma unroll
        for (int mf = 0; mf < 2; ++mf)
#pragma unroll
            for (int s = 0; s < 2; ++s) af[mf][s] = *(const bf16x8*)(Abase + aA[mf][s]);
        __builtin_amdgcn_s_setprio(1);
#pragma unroll
        for (int mf = 0; mf < 2; ++mf)
#pragma unroll
            for (int nf = 0; nf < 2; ++nf)
#pragma unroll
                for (int s = 0; s < 2; ++s)
                    acc[mf][nf] = __builtin_amdgcn_mfma_f32_32x32x16_bf16(af[mf][s], bf[nf][s], acc[mf][nf], 0, 0, 0);
        __builtin_amdgcn_s_setprio(0);
    }
#undef OSTAGE

    // store: 32x32 C/D mapping; lanes 0-31 give 128-B contiguous segments per row
#pragma unroll
    for (int mf = 0; mf < 2; ++mf)
#pragma unroll
        for (int nf = 0; nf < 2; ++nf) {
            int n = nt * 128 + wn * 64 + nf * 32 + m31;
#pragma unroll
            for (int rg = 0; rg < 4; ++rg) {
                int row = mt * 256 + wm * 64 + mf * 32 + rg * 8 + k2 * 4;
#pragma unroll
                for (int r = 0; r < 4; ++r)
                    out[(size_t)(row + r) * 2048 + n] = acc[mf][nf][rg * 4 + r];
            }
        }
}

extern "C" void kernel_launch(void* const* d_in, const int* in_sizes, int n_in,
                              void* d_out, int out_size, void* d_ws, size_t ws_size,
                              hipStream_t stream) {
    const float* x     = (const float*)d_in[0];
    const float* adj   = (const float*)d_in[1];
    const float* Wg    = (const float*)d_in[2];
    const float* Wu    = (const float*)d_in[3];
    const float* Wd    = (const float*)d_in[4];
    const float* eps   = (const float*)d_in[5];
    const float* alpha = (const float*)d_in[6];
    float* out = (float*)d_out;

    unsigned short* ws    = (unsigned short*)d_ws;
    unsigned short* xb    = ws;                               // 4096*2048
    unsigned short* WgT   = xb + (size_t)4096 * 2048;         // 8192*2048
    unsigned short* WuT   = WgT + (size_t)8192 * 2048;        // 8192*2048
    unsigned short* WdT   = WuT + (size_t)8192 * 2048;        // 2048*8192
    unsigned short* hhT   = WdT + (size_t)2048 * 8192;        // 16384*2048
    unsigned short* hcomb = hhT + (size_t)16384 * 2048;       // 4096*8192

    conv_kernel<<<8192, 256, 0, stream>>>(x, xb);
    tconv_kernel<<<4096, 256, 0, stream>>>(Wg, WgT, 2048, 8192);
    tconv_kernel<<<4096, 256, 0, stream>>>(Wu, WuT, 2048, 8192);
    tconv_kernel<<<4096, 256, 0, stream>>>(Wd, WdT, 8192, 2048);
    gemm_gu<<<1024, 512, 0, stream>>>(xb, WgT, WuT, hhT);
    gemm_agg4<<<512, 512, 0, stream>>>(adj, hhT, eps, alpha, hcomb);
    gemm_out2<<<256, 512, 0, stream>>>(hcomb, WdT, out);
}

// Round 14
// 688.947 us; speedup vs baseline: 1.0481x; 1.0481x over previous
//
#include <hip/hip_runtime.h>
#include <hip/hip_bf16.h>

// B=2, S=2048, D=2048, H=16, I=8192, HD=512; M = B*S = 4096.
// r14 = r12 verbatim (best verified: 689.0 us). r13's 32x32x16 experiment was
// correct but regressed (4-way LDS conflict on 128-B-stride fragment reads).

typedef __bf16 bf16x8 __attribute__((ext_vector_type(8)));
typedef float f32x4 __attribute__((ext_vector_type(4)));

__device__ __forceinline__ unsigned short f2bf(float f) {
    union { float f; unsigned int u; } x; x.f = f;
    unsigned int r = x.u + 0x7fffu + ((x.u >> 16) & 1u);  // RNE
    return (unsigned short)(r >> 16);
}
__device__ __forceinline__ float bf2f(unsigned short b) {
    union { unsigned int u; float f; } x; x.u = ((unsigned int)b) << 16;
    return x.f;
}

__device__ __forceinline__ void gload_lds16(const void* g, void* l) {
    __builtin_amdgcn_global_load_lds((const __attribute__((address_space(1))) void*)g,
                                     (__attribute__((address_space(3))) void*)l,
                                     16, 0, 0);
}

// ---------------- prep kernels ----------------

__global__ void conv_kernel(const float* __restrict__ in, unsigned short* __restrict__ out) {
    size_t i = ((size_t)blockIdx.x * 256 + threadIdx.x) * 4;
    float4 v = *(const float4*)(in + i);
    ushort4 o; o.x = f2bf(v.x); o.y = f2bf(v.y); o.z = f2bf(v.z); o.w = f2bf(v.w);
    *(ushort4*)(out + i) = o;
}

__global__ void tconv_kernel(const float* __restrict__ in, unsigned short* __restrict__ out,
                             int R, int C) {
    __shared__ float tile[64][65];
    int nbc = C >> 6;
    int bc = blockIdx.x % nbc, br = blockIdx.x / nbc;
    int r0 = br * 64, c0 = bc * 64;
    int t = threadIdx.x;
#pragma unroll
    for (int i = 0; i < 4; ++i) {
        int idx = i * 256 + t;
        int r = idx >> 4, c4 = (idx & 15) * 4;
        float4 v = *(const float4*)(in + (size_t)(r0 + r) * C + c0 + c4);
        tile[r][c4] = v.x; tile[r][c4 + 1] = v.y; tile[r][c4 + 2] = v.z; tile[r][c4 + 3] = v.w;
    }
    __syncthreads();
#pragma unroll
    for (int i = 0; i < 4; ++i) {
        int idx = i * 256 + t;
        int c = idx >> 4, r4 = (idx & 15) * 4;
        ushort4 o;
        o.x = f2bf(tile[r4][c]); o.y = f2bf(tile[r4 + 1][c]);
        o.z = f2bf(tile[r4 + 2][c]); o.w = f2bf(tile[r4 + 3][c]);
        *(ushort4*)(out + (size_t)(c0 + c) * R + r0 + r4) = o;
    }
}

// ---------------- GEMM 1 fused: gate+up (r9 K-loop; square XCD chunks) ----------------
__global__ void __launch_bounds__(512, 2) gemm_gu(
    const unsigned short* __restrict__ xb,    // 4096 x 2048
    const unsigned short* __restrict__ WgT,   // 8192 x 2048
    const unsigned short* __restrict__ WuT,   // 8192 x 2048
    unsigned short* __restrict__ hhT)         // (2*8192) x 2048
{
    const int K = 2048;
    __shared__ unsigned short LDS[4][16384];  // 128 KB
    int bid = (int)blockIdx.x;
    int xcd = bid & 7, idx = bid >> 3;        // bijective: 1024 = 8 XCD * 128
    int mt = idx & 15;                        // all 16 mt per XCD
    int nt = xcd * 8 + (idx >> 4);            // 8 nt per XCD
    int tid = threadIdx.x, lane = tid & 63, wave = tid >> 6;
    int wm = wave >> 1, wn = wave & 1;        // 4M x 2N waves, wave tile 64x64
    int l15 = lane & 15, l4 = lane >> 4;

    f32x4 accg[4][4] = {};
    f32x4 accu[4][4] = {};

    int jl = (lane & 7) ^ (lane >> 3);
    int prowA = wave * 16 + (lane >> 3);
    int rowA0 = prowA + ((jl & 4) << 5);
    int ccA = (jl & 3) << 3;
    const unsigned short* srcA0 = xb + (size_t)(mt * 256 + rowA0) * K + ccA;
    const unsigned short* srcA1 = srcA0 + (size_t)8 * K;
    int prowB = tid >> 3;
    int jbl = (tid & 7) ^ (prowB & 7);
    int rowB0 = prowB + ((jbl & 4) << 4);
    int ccB = (jbl & 3) << 3;
    const unsigned short* srcBg = WgT + (size_t)(nt * 128 + rowB0) * K + ccB;
    const unsigned short* srcBu = WuT + (size_t)(nt * 128 + rowB0) * K + ccB;

    int cA0 = ((wm & 1) * 64 + l15) * 128 + (((((wm >> 1) << 2) + l4) ^ (l15 & 7)) << 4);
    int cB0 = l15 * 128 + ((((wn << 2) + l4) ^ (l15 & 7)) << 4);

#define GU_STAGE_A(t_) do {                                                              \
        char* dA = (char*)&LDS[(t_) & 3][0] + wave * 2048;                               \
        gload_lds16((const void*)(srcA0 + (size_t)(t_) * 32), (void*)dA);                \
        gload_lds16((const void*)(srcA1 + (size_t)(t_) * 32), (void*)(dA + 1024));       \
    } while (0)
#define GU_STAGE_B(t_) do {                                                              \
        char* dB = (char*)&LDS[(t_) & 3][8192] + wave * 1024;                            \
        gload_lds16((const void*)(srcBg + (size_t)(t_) * 32), (void*)dB);                \
        gload_lds16((const void*)(srcBu + (size_t)(t_) * 32), (void*)(dB + 8192));       \
    } while (0)

    GU_STAGE_A(0); GU_STAGE_B(0);
    GU_STAGE_A(1); GU_STAGE_B(1);
    GU_STAGE_A(2); GU_STAGE_B(2);

    for (int t = 0; t < 64; ++t) {
        if (t + 2 < 64)      asm volatile("s_waitcnt vmcnt(8)" ::: "memory");
        else if (t + 1 < 64) asm volatile("s_waitcnt vmcnt(4)" ::: "memory");
        else                 asm volatile("s_waitcnt vmcnt(0)" ::: "memory");
        __builtin_amdgcn_s_barrier();
        const char* Abase = (const char*)&LDS[t & 3][0];
        bool more = (t + 3) < 64;
        // ---- phase 0: gate ----
        bf16x8 af[4], bfg[4], bfu[4];
#pragma unroll
        for (int ni = 0; ni < 4; ++ni) bfg[ni] = *(const bf16x8*)(Abase + 16384 + cB0 + ni * 2048);
#pragma unroll
        for (int mi = 0; mi < 4; ++mi) af[mi] = *(const bf16x8*)(Abase + cA0 + mi * 2048);
        if (more) GU_STAGE_A(t + 3);
        __builtin_amdgcn_s_barrier();
        asm volatile("s_waitcnt lgkmcnt(0)" ::: "memory");
        __builtin_amdgcn_s_setprio(1);
#pragma unroll
        for (int mi = 0; mi < 4; ++mi)
#pragma unroll
            for (int ni = 0; ni < 4; ++ni)
                accg[mi][ni] = __builtin_amdgcn_mfma_f32_16x16x32_bf16(af[mi], bfg[ni], accg[mi][ni], 0, 0, 0);
        __builtin_amdgcn_s_setprio(0);
        __builtin_amdgcn_s_barrier();
        // ---- phase 1: up (same A-frags) ----
#pragma unroll
        for (int ni = 0; ni < 4; ++ni) bfu[ni] = *(const bf16x8*)(Abase + 24576 + cB0 + ni * 2048);
        if (more) GU_STAGE_B(t + 3);
        __builtin_amdgcn_s_barrier();
        asm volatile("s_waitcnt lgkmcnt(0)" ::: "memory");
        __builtin_amdgcn_s_setprio(1);
#pragma unroll
        for (int mi = 0; mi < 4; ++mi)
#pragma unroll
            for (int ni = 0; ni < 4; ++ni)
                accu[mi][ni] = __builtin_amdgcn_mfma_f32_16x16x32_bf16(af[mi], bfu[ni], accu[mi][ni], 0, 0, 0);
        __builtin_amdgcn_s_setprio(0);
    }
#undef GU_STAGE_A
#undef GU_STAGE_B

    // epilogue: h = silu(g)*u -> hhT
    int rowb = mt * 256 + wm * 64 + l4 * 4;
    int colb = nt * 128 + wn * 64 + l15;
    int b = mt >> 3;
#pragma unroll
    for (int mi = 0; mi < 4; ++mi)
#pragma unroll
        for (int ni = 0; ni < 4; ++ni) {
            int row = rowb + mi * 16;
            int n = colb + ni * 16;
            ushort4 hv;
#pragma unroll
            for (int r = 0; r < 4; ++r) {
                float g = accg[mi][ni][r];
                float u = accu[mi][ni][r];
                float h = g / (1.f + __expf(-g)) * u;
                ((unsigned short*)&hv)[r] = f2bf(h);
            }
            *(ushort4*)(hhT + ((size_t)b * 8192 + n) * 2048 + (row & 2047)) = hv;
        }
}

// ---------------- GEMM 2 v5: agg + GIN (frozen) ----------------
__global__ void __launch_bounds__(512, 2) gemm_agg4(
    const float* __restrict__ adj,            // (B*H=32) x S x S f32
    const unsigned short* __restrict__ hhT,   // (B*I) x S bf16
    const float* __restrict__ eps, const float* __restrict__ alpha,
    unsigned short* __restrict__ hcomb)       // (B*S) x I bf16
{
    const int S = 2048, HD = 512, I = 8192;
    __shared__ unsigned short As[2][128 * 40];   // 2 x 10 KB, padded 80B rows
    __shared__ unsigned short Bs[4][512 * 32];   // 4 x 32 KB, paired-row swizzled
    int bid = (int)blockIdx.x;
    int lb = (bid & 7) * 64 + (bid >> 3);
    int pair = lb >> 4;
    int mt = lb & 15;
    int b = pair >> 4, h = pair & 15;
    int tid = threadIdx.x, lane = tid & 63, wave = tid >> 6;
    int wm = wave >> 2, wn = wave & 3;
    int l15 = lane & 15, l4 = lane >> 4;
    f32x4 acc[4][8] = {};

    float e1 = 1.f + eps[h];
    float a1 = alpha[h];
    bool a1z = (a1 == 0.f);
    float dfac = a1z ? 0.f : (e1 / a1);

    const float* Ab = adj + ((size_t)pair * S + (size_t)mt * 128) * S;
    const unsigned short* Bb = hhT + ((size_t)b * I + (size_t)h * HD) * (size_t)S;

    int a_row0 = tid >> 3, a_c = (tid & 7) << 2;
    int grow0 = mt * 128 + a_row0;

    int jl = (lane & 7) ^ (lane >> 3);
    int prow0 = wave * 16 + (lane >> 3);
    int browB = prow0 + ((jl & 4) << 6);
    int ccB = (jl & 3) << 3;
    const unsigned short* srcB = Bb + (size_t)browB * S + ccB;

#define BSTAGE(t_) do {                                                           \
        char* d_ = (char*)&Bs[(t_) & 3][0] + wave * 2048;                         \
        const unsigned short* s_ = srcB + (size_t)(t_) * 32;                      \
        gload_lds16((const void*)s_, (void*)d_);                                  \
        gload_lds16((const void*)(s_ + (size_t)8 * S), (void*)(d_ + 1024));       \
        gload_lds16((const void*)(s_ + (size_t)128 * S), (void*)(d_ + 16384));    \
        gload_lds16((const void*)(s_ + (size_t)136 * S), (void*)(d_ + 17408));    \
    } while (0)

    float4 pa0_0, pa1_0, pa0_1, pa1_1;

#define ALOAD(SET, K0)                                                            \
    do {                                                                          \
        pa0_##SET = *(const float4*)(Ab + (size_t)a_row0 * S + (K0) + a_c);       \
        pa1_##SET = *(const float4*)(Ab + (size_t)(a_row0 + 64) * S + (K0) + a_c);\
    } while (0)

#define ACONV(SET, BUF, K0)                                                       \
    do {                                                                          \
        int j0 = grow0 - (K0) - a_c;                                              \
        pa0_##SET.x += (j0 == 0) ? dfac : 0.f;                                    \
        pa0_##SET.y += (j0 == 1) ? dfac : 0.f;                                    \
        pa0_##SET.z += (j0 == 2) ? dfac : 0.f;                                    \
        pa0_##SET.w += (j0 == 3) ? dfac : 0.f;                                    \
        int j1 = j0 + 64;                                                         \
        pa1_##SET.x += (j1 == 0) ? dfac : 0.f;                                    \
        pa1_##SET.y += (j1 == 1) ? dfac : 0.f;                                    \
        pa1_##SET.z += (j1 == 2) ? dfac : 0.f;                                    \
        pa1_##SET.w += (j1 == 3) ? dfac : 0.f;                                    \
        ushort4 o0, o1;                                                           \
        o0.x = f2bf(pa0_##SET.x); o0.y = f2bf(pa0_##SET.y);                       \
        o0.z = f2bf(pa0_##SET.z); o0.w = f2bf(pa0_##SET.w);                       \
        o1.x = f2bf(pa1_##SET.x); o1.y = f2bf(pa1_##SET.y);                       \
        o1.z = f2bf(pa1_##SET.z); o1.w = f2bf(pa1_##SET.w);                       \
        *(ushort4*)((char*)As[BUF] + a_row0 * 80 + a_c * 2) = o0;                 \
        *(ushort4*)((char*)As[BUF] + (a_row0 + 64) * 80 + a_c * 2) = o1;          \
    } while (0)

    int koff2 = l4 << 4;
    const char* aptr0 = (const char*)As[0] + (wm * 64 + l15) * 80 + koff2;
    const char* aptr1 = (const char*)As[1] + (wm * 64 + l15) * 80 + koff2;
    int cB = ((wn & 1) * 128 + l15) * 128 + (((l4 + ((wn >> 1) << 2)) ^ (l15 & 7)) << 4);

#define AGG_COMPUTE(APTR, BBASE)                                                        \
    do {                                                                                \
        bf16x8 af[4], bfv[8];                                                           \
        _Pragma("unroll")                                                               \
        for (int mi = 0; mi < 4; ++mi) af[mi] = *(const bf16x8*)((APTR) + mi * 16 * 80);\
        _Pragma("unroll")                                                               \
        for (int ni = 0; ni < 8; ++ni) bfv[ni] = *(const bf16x8*)((BBASE) + cB + ni * 2048);\
        __builtin_amdgcn_s_setprio(1);                                                  \
        _Pragma("unroll")                                                               \
        for (int mi = 0; mi < 4; ++mi)                                                  \
            _Pragma("unroll")                                                           \
            for (int ni = 0; ni < 8; ++ni)                                              \
                acc[mi][ni] = __builtin_amdgcn_mfma_f32_16x16x32_bf16(af[mi], bfv[ni],  \
                                                                      acc[mi][ni], 0, 0, 0); \
        __builtin_amdgcn_s_setprio(0);                                                  \
    } while (0)

    BSTAGE(0);
    ALOAD(0, 0);
    BSTAGE(1);
    ALOAD(1, 32);
    BSTAGE(2);
    ACONV(0, 0, 0);
    asm volatile("s_waitcnt lgkmcnt(0)" ::: "memory");
    __builtin_amdgcn_s_barrier();

    for (int s = 0; s < 64; s += 2) {
        AGG_COMPUTE(aptr0, (const char*)&Bs[s & 3][0]);
        ACONV(1, 1, (s + 1) * 32);
        if (s + 2 < 64) ALOAD(0, (s + 2) * 32);
        if (s + 3 < 64) BSTAGE(s + 3);
        asm volatile("s_waitcnt lgkmcnt(0)" ::: "memory");
        __builtin_amdgcn_s_barrier();
        AGG_COMPUTE(aptr1, (const char*)&Bs[(s + 1) & 3][0]);
        if (s + 2 < 64) {
            ACONV(0, 0, (s + 2) * 32);
            if (s + 3 < 64) ALOAD(1, (s + 3) * 32);
            if (s + 4 < 64) BSTAGE(s + 4);
            asm volatile("s_waitcnt lgkmcnt(0)" ::: "memory");
            __builtin_amdgcn_s_barrier();
        }
    }
#undef BSTAGE
#undef ALOAD
#undef ACONV
#undef AGG_COMPUTE

    int s_base = mt * 128 + wm * 64;
    int d_base = wn * 128;
    if (!a1z) {
#pragma unroll
        for (int mi = 0; mi < 4; ++mi)
#pragma unroll
            for (int ni = 0; ni < 8; ++ni) {
                int sb = s_base + mi * 16 + ((lane >> 4) << 2);
                int d = d_base + ni * 16 + (lane & 15);
#pragma unroll
                for (int r = 0; r < 4; ++r) {
                    size_t off = ((size_t)(b * S + sb + r)) * I + (size_t)h * HD + d;
                    hcomb[off] = f2bf(a1 * acc[mi][ni][r]);
                }
            }
    } else {
        // alpha == 0 fallback (never taken in bench)
#pragma unroll
        for (int mi = 0; mi < 4; ++mi)
#pragma unroll
            for (int ni = 0; ni < 8; ++ni) {
                int sb = s_base + mi * 16 + ((lane >> 4) << 2);
                int d = d_base + ni * 16 + (lane & 15);
                size_t col = (size_t)h * HD + d;
                ushort4 hq = *(const ushort4*)(hhT + ((size_t)b * I + col) * S + sb);
#pragma unroll
                for (int r = 0; r < 4; ++r) {
                    size_t off = ((size_t)(b * S + sb + r)) * I + col;
                    hcomb[off] = f2bf(e1 * bf2f(((const unsigned short*)&hq)[r]));
                }
            }
    }
}

// ---------------- GEMM 3: final projection (square XCD chunks, frozen) ----------------
__global__ void __launch_bounds__(512, 2) gemm_out2(
    const unsigned short* __restrict__ hcomb, // 4096 x 8192
    const unsigned short* __restrict__ WdT,   // 2048 x 8192
    float* __restrict__ out)                  // 4096 x 2048
{
    const int K = 8192;
    __shared__ unsigned short LDS[6][12288];  // 144 KB: per buf A 16 KB + B 8 KB
    int bid = (int)blockIdx.x;
    int xcd = bid & 7, idx = bid >> 3;        // bijective: 256 = 8 XCD * 32
    int mt = (xcd >> 1) * 4 + (idx & 3);      // 4 mt per XCD
    int nt = (xcd & 1) * 8 + (idx >> 2);      // 8 nt per XCD
    int tid = threadIdx.x, lane = tid & 63, wave = tid >> 6;
    int wm = wave >> 1, wn = wave & 1;
    int l15 = lane & 15, l4 = lane >> 4;
    f32x4 acc[4][4] = {};

    int jl = (lane & 7) ^ (lane >> 3);
    int prowA = wave * 16 + (lane >> 3);
    int rowA0 = prowA + ((jl & 4) << 5);
    int ccA = (jl & 3) << 3;
    const unsigned short* srcA0 = hcomb + (size_t)(mt * 256 + rowA0) * K + ccA;
    const unsigned short* srcA1 = srcA0 + (size_t)8 * K;
    int prowB = tid >> 3;
    int jbl = (tid & 7) ^ (prowB & 7);
    int rowB0 = prowB + ((jbl & 4) << 4);
    int ccB = (jbl & 3) << 3;
    const unsigned short* srcB0 = WdT + (size_t)(nt * 128 + rowB0) * K + ccB;

    int cA0 = ((wm & 1) * 64 + l15) * 128 + (((((wm >> 1) << 2) + l4) ^ (l15 & 7)) << 4);
    int cB0 = l15 * 128 + ((((wn << 2) + l4) ^ (l15 & 7)) << 4);

#define OSTAGE(t_) do {                                                                  \
        char* dA = (char*)&LDS[(t_) % 6][0] + wave * 2048;                               \
        gload_lds16((const void*)(srcA0 + (size_t)(t_) * 32), (void*)dA);                \
        gload_lds16((const void*)(srcA1 + (size_t)(t_) * 32), (void*)(dA + 1024));       \
        char* dB = (char*)&LDS[(t_) % 6][8192] + wave * 1024;                            \
        gload_lds16((const void*)(srcB0 + (size_t)(t_) * 32), (void*)dB);                \
    } while (0)

    OSTAGE(0); OSTAGE(1); OSTAGE(2); OSTAGE(3);

    for (int t = 0; t < 256; ++t) {
        if (t + 3 < 256)      asm volatile("s_waitcnt vmcnt(9)" ::: "memory");
        else if (t + 2 < 256) asm volatile("s_waitcnt vmcnt(6)" ::: "memory");
        else if (t + 1 < 256) asm volatile("s_waitcnt vmcnt(3)" ::: "memory");
        else                  asm volatile("s_waitcnt vmcnt(0)" ::: "memory");
        __builtin_amdgcn_s_barrier();
        const char* Abase = (const char*)&LDS[t % 6][0];
        const char* Bbase = Abase + 16384;
        bool more = (t + 4) < 256;
        bf16x8 af[4], bf[4];
#pragma unroll
        for (int ni = 0; ni < 4; ++ni) bf[ni] = *(const bf16x8*)(Bbase + cB0 + ni * 2048);
        if (more) OSTAGE(t + 4);
#pragma unroll
        for (int mi = 0; mi < 4; ++mi) af[mi] = *(const bf16x8*)(Abase + cA0 + mi * 2048);
        __builtin_amdgcn_s_setprio(1);
#pragma unroll
        for (int mi = 0; mi < 4; ++mi)
#pragma unroll
            for (int ni = 0; ni < 4; ++ni)
                acc[mi][ni] = __builtin_amdgcn_mfma_f32_16x16x32_bf16(af[mi], bf[ni], acc[mi][ni], 0, 0, 0);
        __builtin_amdgcn_s_setprio(0);
    }
#undef OSTAGE

    int m_off = mt * 256 + wm * 64, n_off = nt * 128 + wn * 64;
#pragma unroll
    for (int mi = 0; mi < 4; ++mi)
#pragma unroll
        for (int ni = 0; ni < 4; ++ni) {
            int mbase = m_off + mi * 16 + l4 * 4;
            int n = n_off + ni * 16 + l15;
#pragma unroll
            for (int r = 0; r < 4; ++r)
                out[(size_t)(mbase + r) * 2048 + n] = acc[mi][ni][r];
        }
}

extern "C" void kernel_launch(void* const* d_in, const int* in_sizes, int n_in,
                              void* d_out, int out_size, void* d_ws, size_t ws_size,
                              hipStream_t stream) {
    const float* x     = (const float*)d_in[0];
    const float* adj   = (const float*)d_in[1];
    const float* Wg    = (const float*)d_in[2];
    const float* Wu    = (const float*)d_in[3];
    const float* Wd    = (const float*)d_in[4];
    const float* eps   = (const float*)d_in[5];
    const float* alpha = (const float*)d_in[6];
    float* out = (float*)d_out;

    unsigned short* ws    = (unsigned short*)d_ws;
    unsigned short* xb    = ws;                               // 4096*2048
    unsigned short* WgT   = xb + (size_t)4096 * 2048;         // 8192*2048
    unsigned short* WuT   = WgT + (size_t)8192 * 2048;        // 8192*2048
    unsigned short* WdT   = WuT + (size_t)8192 * 2048;        // 2048*8192
    unsigned short* hhT   = WdT + (size_t)2048 * 8192;        // 16384*2048
    unsigned short* hcomb = hhT + (size_t)16384 * 2048;       // 4096*8192

    conv_kernel<<<8192, 256, 0, stream>>>(x, xb);
    tconv_kernel<<<4096, 256, 0, stream>>>(Wg, WgT, 2048, 8192);
    tconv_kernel<<<4096, 256, 0, stream>>>(Wu, WuT, 2048, 8192);
    tconv_kernel<<<4096, 256, 0, stream>>>(Wd, WdT, 8192, 2048);
    gemm_gu<<<1024, 512, 0, stream>>>(xb, WgT, WuT, hhT);
    gemm_agg4<<<512, 512, 0, stream>>>(adj, hhT, eps, alpha, hcomb);
    gemm_out2<<<256, 512, 0, stream>>>(hcomb, WdT, out);
}